// Round 5
// baseline (530.125 us; speedup 1.0000x reference)
//
#include <hip/hip_runtime.h>

typedef unsigned short u16;
typedef short bf16x8 __attribute__((ext_vector_type(8)));
typedef float f32x4 __attribute__((ext_vector_type(4)));

__device__ inline u16 f2bf(float f) {
  unsigned u = __float_as_uint(f);
  u += 0x7fff + ((u >> 16) & 1);
  return (u16)(u >> 16);
}

__device__ inline void gl_lds16(const u16* g, u16* l) {
  __builtin_amdgcn_global_load_lds((const __attribute__((address_space(1))) void*)g,
                                   (__attribute__((address_space(3))) void*)l, 16, 0, 0);
}

// ---------------- fused prep: transposes + weight prep in ONE launch ----------------
// blocks [0,1024): anchor transpose; [1024,2048): positive transpose; [2048,2560): weights.
__global__ __launch_bounds__(256) void prep_all(const float* __restrict__ anchor,
                                                const float* __restrict__ positive,
                                                u16* __restrict__ A_t, u16* __restrict__ Pos_t,
                                                const float* __restrict__ Ww,
                                                const float* __restrict__ W2,
                                                const float* __restrict__ b2,
                                                const float* __restrict__ W1,
                                                u16* __restrict__ W2p, float* __restrict__ b2p,
                                                u16* __restrict__ W1b, u16* __restrict__ Wwb) {
  __shared__ u16 T[64 * 256];  // 32 KB, chunk-swizzled: chunk(p,cc) = p*32 + (cc ^ ((p>>2)&15))
  const int tid = threadIdx.x;

  if (blockIdx.x >= 2048) {  // ---- weight prep ----
    int g = (blockIdx.x - 2048) * 256 + tid;  // 131072 threads
    W1b[g] = f2bf(W1[g]);
    if (g < 65536) Wwb[g] = f2bf(Ww[g]);
    int d = g >> 9, h = g & 511;
    float s = 0.f;
    for (int c = 0; c < 256; c++) s += Ww[d * 256 + c] * W2[c * 512 + h];
    W2p[g] = f2bf(s);
    if (g < 256) {
      float t = 0.f;
      for (int c = 0; c < 256; c++) t += Ww[g * 256 + c] * b2[c];
      b2p[g] = t;
    }
    return;
  }

  // ---- transpose: [1024 b][256 c][64 p] fp32 -> [64 p][1024 b][256 c] bf16 ----
  const float* in = (blockIdx.x & 1024) ? positive : anchor;
  u16* outp = (blockIdx.x & 1024) ? Pos_t : A_t;
  const int b = blockIdx.x & 1023;
  const f32x4* in4 = (const f32x4*)in + (size_t)b * 4096;

  #pragma unroll
  for (int i = 0; i < 16; i++) {
    int local = i * 256 + tid;
    int c = local >> 4;            // 0..255
    int p4 = (local & 15) << 2;    // 0..60
    f32x4 v = __builtin_nontemporal_load(&in4[local]);
    int cc = c >> 3, co = c & 7;
    #pragma unroll
    for (int k = 0; k < 4; k++) {
      int p = p4 + k;
      int chunk = p * 32 + (cc ^ ((p >> 2) & 15));
      T[chunk * 8 + co] = f2bf(v[k]);
    }
  }
  __syncthreads();

  u16* ob = outp + (size_t)b * 256;
  #pragma unroll
  for (int j = 0; j < 8; j++) {
    int idx = j * 256 + tid;       // chunk id: 32 chunks per row
    int row = idx >> 5;            // p
    int col16 = idx & 31;          // cc
    int chunk = row * 32 + (col16 ^ ((row >> 2) & 15));
    bf16x8 vv = *(const bf16x8*)&T[chunk * 8];
    *(bf16x8*)&ob[((size_t)row << 18) + col16 * 8] = vv;
  }
}

// ---------------- generic bf16 GEMM: C = epi(A1@B1^T + A2@B2^T + bias) ----------------
// BK=32, 3-buffer 2-deep staging pipeline with counted vmcnt: iter kt issues stage(kt+2),
// computes buf[kt%3], then s_waitcnt vmcnt(4) + raw barrier (4 = the just-issued stage's
// loads; <=4 outstanding => stage kt+1 retired). Loads stay in flight across barriers.
// LDS 3*(8+8) KB = 48 KB -> still 3 blocks/CU. XCD remap as before.
__global__ __launch_bounds__(256, 3)
void gemm_bt(const u16* __restrict__ A1, const u16* __restrict__ B1, int nkt1, int K1,
             const u16* __restrict__ A2, const u16* __restrict__ B2, int nkt2, int K2,
             const float* __restrict__ bias, u16* __restrict__ C, int N, int relu,
             int lognbx) {
  __shared__ u16 As[3][128 * 32];
  __shared__ u16 Bs[3][128 * 32];
  const int tid = threadIdx.x;
  const int lane = tid & 63;
  const int wave = tid >> 6;
  const int wm = wave & 1;
  const int wn = wave >> 1;
  const int i_d = blockIdx.y * gridDim.x + blockIdx.x;
  const int xcd = i_d & 7;
  const int slot = i_d >> 3;
  const int bx = slot & ((1 << lognbx) - 1);
  const int by = xcd * (gridDim.y >> 3) + (slot >> lognbx);
  const int m0 = by * 128;
  const int n0 = bx * 128;
  const int q = lane >> 4;
  const int l15 = lane & 15;
  const int nkt = nkt1 + nkt2;

  // stage one 128x32 A-tile + B-tile into buffer `buf`; 512 chunks of 16B each array,
  // 4 chunks/row; LDS slot (row, cc) holds global col-group cc^(row&3).
  auto stageF = [&](int kt, int buf) {
    const u16* A; const u16* B; int K, k0;
    if (kt < nkt1) { A = A1; B = B1; K = K1; k0 = kt << 5; }
    else           { A = A2; B = B2; K = K2; k0 = (kt - nkt1) << 5; }
    #pragma unroll
    for (int c = 0; c < 2; c++) {
      int chunk = c * 256 + tid;     // 0..511
      int row = chunk >> 2;
      int cg = (chunk & 3) ^ (row & 3);
      gl_lds16(A + (size_t)(m0 + row) * K + k0 + cg * 8, &As[buf][chunk * 8]);
      gl_lds16(B + (size_t)(n0 + row) * K + k0 + cg * 8, &Bs[buf][chunk * 8]);
    }
  };

  f32x4 acc[4][4];
  #pragma unroll
  for (int i = 0; i < 4; i++)
    #pragma unroll
    for (int j = 0; j < 4; j++) acc[i][j] = (f32x4)(0.0f);

  stageF(0, 0);
  stageF(1, 1);
  asm volatile("s_waitcnt vmcnt(4)" ::: "memory");  // stage0 retired
  __builtin_amdgcn_s_barrier();

  int cur = 0;
  for (int kt = 0; kt < nkt; kt++) {
    if (kt + 2 < nkt) stageF(kt + 2, cur == 0 ? 2 : cur - 1);

    bf16x8 af[4], bfr[4];
    #pragma unroll
    for (int i = 0; i < 4; i++) {
      int row = wm * 64 + i * 16 + l15;
      af[i] = *(const bf16x8*)&As[cur][row * 32 + ((q ^ (row & 3)) * 8)];
    }
    #pragma unroll
    for (int j = 0; j < 4; j++) {
      int row = wn * 64 + j * 16 + l15;
      bfr[j] = *(const bf16x8*)&Bs[cur][row * 32 + ((q ^ (row & 3)) * 8)];
    }
    #pragma unroll
    for (int i = 0; i < 4; i++)
      #pragma unroll
      for (int j = 0; j < 4; j++)
        acc[i][j] = __builtin_amdgcn_mfma_f32_16x16x32_bf16(af[i], bfr[j], acc[i][j], 0, 0, 0);

    if (kt + 1 < nkt) {
      if (kt + 2 < nkt) asm volatile("s_waitcnt vmcnt(4)" ::: "memory");  // kt+1 retired
      else              asm volatile("s_waitcnt vmcnt(0)" ::: "memory");  // drain tail
      __builtin_amdgcn_s_barrier();
    }
    cur = (cur == 2) ? 0 : cur + 1;
  }

  float bv[4];
  #pragma unroll
  for (int j = 0; j < 4; j++) bv[j] = bias[n0 + wn * 64 + j * 16 + l15];

  #pragma unroll
  for (int i = 0; i < 4; i++) {
    #pragma unroll
    for (int r = 0; r < 4; r++) {
      int row = m0 + wm * 64 + i * 16 + q * 4 + r;
      u16* crow = C + (size_t)row * N + n0 + wn * 64 + l15;
      #pragma unroll
      for (int j = 0; j < 4; j++) {
        float v = acc[i][j][r] + bv[j];
        if (relu) v = fmaxf(v, 0.0f);
        crow[j * 16] = f2bf(v);
      }
    }
  }
}

// ---------------- fused logits + rowmax ----------------
// Block remap: L = by*16+bx; p = (L&7) + 8*(L>>7); mtile = (L>>3)&15.
// All 16 blocks sharing post[p] land on the same XCD; out stores non-temporal.
__global__ __launch_bounds__(512, 2)
void logits_k(const u16* __restrict__ pred, const u16* __restrict__ post,
              float* __restrict__ out) {
  __shared__ u16 As[64 * 256];       // 32 KB
  __shared__ float pmax[8][64];
  const int tid = threadIdx.x;
  const int lane = tid & 63;
  const int wave = tid >> 6;
  const int q = lane >> 4;
  const int l15 = lane & 15;
  const int L = blockIdx.y * 16 + blockIdx.x;
  const int p = (L & 7) + ((L >> 7) << 3);
  const int m0 = ((L >> 3) & 15) * 64;
  const u16* Ap = pred + (((size_t)p * 1024 + m0) << 8);
  const u16* Bp = post + ((size_t)p << 18);

  // stage A: 64 rows x 256 cols = 2048 chunks of 16B; swizzle chunk^(row&7)
  #pragma unroll
  for (int c = 0; c < 4; c++) {
    int chunk = c * 512 + tid;   // 32 chunks per row
    int row = chunk >> 5;
    int cg = (chunk & 31) ^ (row & 7);
    gl_lds16(Ap + row * 256 + cg * 8, &As[chunk * 8]);
  }

  f32x4 acc[4][8];
  #pragma unroll
  for (int i = 0; i < 4; i++)
    #pragma unroll
    for (int j = 0; j < 8; j++) acc[i][j] = (f32x4)(0.0f);

  __syncthreads();

  const int nbase = wave * 128;
  #pragma unroll
  for (int kt = 0; kt < 8; kt++) {
    bf16x8 bfr[8];
    #pragma unroll
    for (int j = 0; j < 8; j++) {
      int n = nbase + j * 16 + l15;
      bfr[j] = *(const bf16x8*)&Bp[(size_t)n * 256 + kt * 32 + q * 8];
    }
    bf16x8 afr[4];
    #pragma unroll
    for (int i = 0; i < 4; i++) {
      int row = i * 16 + l15;
      afr[i] = *(const bf16x8*)&As[row * 256 + ((((kt << 2) + q) ^ (row & 7)) * 8)];
    }
    #pragma unroll
    for (int i = 0; i < 4; i++)
      #pragma unroll
      for (int j = 0; j < 8; j++)
        acc[i][j] = __builtin_amdgcn_mfma_f32_16x16x32_bf16(afr[i], bfr[j], acc[i][j], 0, 0, 0);
  }

  // rowmax: per-lane over 8 n-tiles, then across the 16 col-lanes, then across waves
  float rm[4][4];
  #pragma unroll
  for (int i = 0; i < 4; i++)
    #pragma unroll
    for (int r = 0; r < 4; r++) {
      float m = acc[i][0][r];
      #pragma unroll
      for (int j = 1; j < 8; j++) m = fmaxf(m, acc[i][j][r]);
      m = fmaxf(m, __shfl_xor(m, 1, 64));
      m = fmaxf(m, __shfl_xor(m, 2, 64));
      m = fmaxf(m, __shfl_xor(m, 4, 64));
      m = fmaxf(m, __shfl_xor(m, 8, 64));
      rm[i][r] = m;
    }
  if (l15 == 0) {
    #pragma unroll
    for (int i = 0; i < 4; i++)
      #pragma unroll
      for (int r = 0; r < 4; r++) pmax[wave][i * 16 + q * 4 + r] = rm[i][r];
  }
  __syncthreads();
  #pragma unroll
  for (int i = 0; i < 4; i++)
    #pragma unroll
    for (int r = 0; r < 4; r++) {
      int row = i * 16 + q * 4 + r;
      float m = pmax[0][row];
      #pragma unroll
      for (int w = 1; w < 8; w++) m = fmaxf(m, pmax[w][row]);
      rm[i][r] = m;
    }

  float* ob = out + ((size_t)p << 20) + (size_t)m0 * 1024 + nbase + l15;
  #pragma unroll
  for (int i = 0; i < 4; i++)
    #pragma unroll
    for (int r = 0; r < 4; r++) {
      float* orow = ob + (size_t)(i * 16 + q * 4 + r) * 1024;
      #pragma unroll
      for (int j = 0; j < 8; j++)
        __builtin_nontemporal_store(acc[i][j][r] - rm[i][r], &orow[j * 16]);
    }
}

// ---------------- launch ----------------

extern "C" void kernel_launch(void* const* d_in, const int* in_sizes, int n_in,
                              void* d_out, int out_size, void* d_ws, size_t ws_size,
                              hipStream_t stream) {
  const float* anchor   = (const float*)d_in[0];
  const float* positive = (const float*)d_in[1];
  const float* W1       = (const float*)d_in[2];
  const float* b1       = (const float*)d_in[3];
  const float* W2       = (const float*)d_in[4];
  const float* b2       = (const float*)d_in[5];
  const float* Ww       = (const float*)d_in[6];
  float* out = (float*)d_out;
  char* ws = (char*)d_ws;

  u16*   A_t    = (u16*)(ws + 0x00000000);  // 32 MB  [64][1024][256] bf16
  u16*   Pos_t  = (u16*)(ws + 0x02000000);  // 32 MB
  u16*   hidden = (u16*)(ws + 0x04000000);  // 64 MB  [65536][512] bf16
  u16*   pred   = (u16*)(ws + 0x08000000);  // 32 MB  [64][1024][256] bf16
  u16*   W1b    = (u16*)(ws + 0x0A000000);  // 256 KB
  u16*   Wwb    = (u16*)(ws + 0x0A100000);  // 128 KB
  u16*   W2pb   = (u16*)(ws + 0x0A200000);  // 512 KB
  float* b2p    = (float*)(ws + 0x0A300000);

  // transposes + weight prep in one launch
  prep_all<<<2560, 256, 0, stream>>>(anchor, positive, A_t, Pos_t,
                                     Ww, W2, b2, W1, W2pb, b2p, W1b, Wwb);

  // hidden = relu(A_t @ W1^T + b1): M=65536, N=512, K=256 (8 kt of 32)
  gemm_bt<<<dim3(4, 512), 256, 0, stream>>>(A_t, W1b, 8, 256, nullptr, nullptr, 0, 512,
                                            b1, hidden, 512, 1, 2);
  // pred = A_t @ Ww^T + hidden @ W2p^T + b2p: M=65536, N=256 (8 + 16 kt)
  gemm_bt<<<dim3(2, 512), 256, 0, stream>>>(A_t, Wwb, 8, 256, hidden, W2pb, 16, 512,
                                            b2p, pred, 256, 0, 1);
  // logits + rowmax
  logits_k<<<dim3(16, 64), 512, 0, stream>>>(pred, Pos_t, out);
}